// Round 9
// baseline (283.738 us; speedup 1.0000x reference)
//
#include <hip/hip_runtime.h>
#include <stdint.h>

typedef __attribute__((ext_vector_type(8))) short short8;
typedef __attribute__((ext_vector_type(4))) float float4v;

#define HW   4096
#define CC   256
#define SEQQ 32
#define BSZ  32
#define RPB  128   // rows per block (4 waves x 32 rows)

// Tiled ctx layout (per batch): [s>>2][c>>4][s&3][c&15] shorts.
// s-group = 16 c-tiles x 64 = 1024 shorts, padded to 1032 (bank de-phase).
#define SGRP     1032
#define CTXT_SZ  (8 * SGRP)          // 8256 shorts per batch

static __device__ __forceinline__ uint16_t f2bf(float f) {
  union { float f; uint32_t u; } v; v.f = f;
  uint32_t r = v.u + 0x7FFFu + ((v.u >> 16) & 1u);
  return (uint16_t)(r >> 16);
}
static __device__ __forceinline__ float bf2f(uint16_t h) {
  union { uint32_t u; float f; } v; v.u = ((uint32_t)h) << 16;
  return v.f;
}

// ---------------------------------------------------------------------------
// Prep: ctx = context @ W (fp32 accum), split to bf16 hi/lo in TILED layout,
// plus mask -> 32-word bitmask (with storage-format autodetection).
// ---------------------------------------------------------------------------
extern "C" __global__ __launch_bounds__(256) void prep_kernel(
    const float* __restrict__ ctx_in,   // [32][32][256]
    const float* __restrict__ Wp,       // [256][256]
    const void*  __restrict__ mask,     // [32][32] unknown storage
    uint32_t* __restrict__ maskbits_ws, // [32] bitmask words
    uint16_t* __restrict__ hiT_ws,      // [32][8256] tiled bf16 hi
    uint16_t* __restrict__ loT_ws)      // [32][8256] tiled bf16 lo
{
  const int t = threadIdx.x;
  if (blockIdx.x == 256) {
    __shared__ int byteFlag;
    if (t == 0) byteFlag = 0;
    __syncthreads();
    const uint8_t* mb = (const uint8_t*)mask;
    int nz = 0;
    for (int i = t; i < 1024; i += 256)
      if ((i & 3) == 1 && mb[i] != 0) nz = 1;
    if (nz) atomicOr(&byteFlag, 1);
    __syncthreads();
    const bool byteMode = (byteFlag != 0);
    const uint32_t* mw32 = (const uint32_t*)mask;
    if (t < 32) {
      uint32_t bits = 0;
      for (int s = 0; s < 32; ++s) {
        bool m = byteMode ? (mb[t * 32 + s] != 0) : (mw32[t * 32 + s] != 0);
        if (m) bits |= (1u << s);
      }
      maskbits_ws[t] = bits;
    }
    return;
  }

  const int r0 = blockIdx.x * 4;
  __shared__ float crow[4][CC];
  for (int i = t; i < 1024; i += 256)
    crow[i >> 8][i & 255] = ctx_in[(size_t)r0 * CC + i];
  __syncthreads();

  const int j  = t >> 6;
  const int c4 = (t & 63) << 2;
  float4v acc = {0.f, 0.f, 0.f, 0.f};
  #pragma unroll 8
  for (int d = 0; d < CC; ++d) {
    float s = crow[j][d];
    const float4 wv = *(const float4*)&Wp[(size_t)d * CC + c4];
    acc[0] += s * wv.x; acc[1] += s * wv.y;
    acc[2] += s * wv.z; acc[3] += s * wv.w;
  }

  const int row = r0 + j, bb = row >> 5, ss = row & 31;
  const size_t base = (size_t)bb * CTXT_SZ + (ss >> 2) * SGRP + (ss & 3) * 16;
  #pragma unroll
  for (int q = 0; q < 4; ++q) {
    const int c = c4 + q;
    const float v = acc[q];
    const uint16_t h  = f2bf(v);
    const uint16_t lo = f2bf(v - bf2f(h));
    const size_t idx = base + (c >> 4) * 64 + (c & 15);
    hiT_ws[idx] = h;
    loT_ws[idx] = lo;
  }
}

// Phase-1 tile: split-bf16 MFMA logits + softmax + out1 (fp32 P) only.
// Byte-identical math to the r4 kernel; phase 2 moved to attn_p2.
#define COMPUTE_TILE_P1(XA, XB, TBASE)                                        \
  {                                                                           \
    float4v acc0 = {0.f, 0.f, 0.f, 0.f};                                      \
    float4v acc1 = {0.f, 0.f, 0.f, 0.f};                                      \
    _Pragma("unroll")                                                         \
    for (int k0 = 0; k0 < 8; ++k0) {                                          \
      float xv[8] = {XA[k0].x, XA[k0].y, XA[k0].z, XA[k0].w,                  \
                     XB[k0].x, XB[k0].y, XB[k0].z, XB[k0].w};                 \
      short8 ah, al;                                                          \
      _Pragma("unroll")                                                       \
      for (int jj = 0; jj < 8; ++jj) {                                        \
        uint32_t u = __float_as_uint(xv[jj]);                                 \
        ah[jj] = (short)(u >> 16);                                            \
        float rr_ = xv[jj] - __uint_as_float(u & 0xFFFF0000u);                \
        al[jj] = (short)(__float_as_uint(rr_) >> 16);                         \
      }                                                                       \
      const int ka = sbase + k0 * 128;                                        \
      short8 bh0 = *(const short8*)&hiT[ka];                                  \
      short8 bl0 = *(const short8*)&loT[ka];                                  \
      short8 bh1 = *(const short8*)&hiT[ka + 4 * SGRP];                       \
      short8 bl1 = *(const short8*)&loT[ka + 4 * SGRP];                       \
      acc0 = __builtin_amdgcn_mfma_f32_16x16x32_bf16(bh0, ah, acc0, 0, 0, 0); \
      acc0 = __builtin_amdgcn_mfma_f32_16x16x32_bf16(bl0, ah, acc0, 0, 0, 0); \
      acc0 = __builtin_amdgcn_mfma_f32_16x16x32_bf16(bh0, al, acc0, 0, 0, 0); \
      acc1 = __builtin_amdgcn_mfma_f32_16x16x32_bf16(bh1, ah, acc1, 0, 0, 0); \
      acc1 = __builtin_amdgcn_mfma_f32_16x16x32_bf16(bl1, ah, acc1, 0, 0, 0); \
      acc1 = __builtin_amdgcn_mfma_f32_16x16x32_bf16(bh1, al, acc1, 0, 0, 0); \
    }                                                                         \
    const int n = (TBASE) + l15;                                              \
    const uint32_t mwd = maskW[n & 31];                                       \
    float v[8];                                                               \
    _Pragma("unroll")                                                         \
    for (int r = 0; r < 4; ++r) {                                             \
      v[r]     = (mwd & (1u << (quad * 4 + r)))      ? -1e30f : acc0[r];      \
      v[4 + r] = (mwd & (1u << (16 + quad * 4 + r))) ? -1e30f : acc1[r];      \
    }                                                                         \
    float mx = v[0];                                                          \
    _Pragma("unroll")                                                         \
    for (int jq = 1; jq < 8; ++jq) mx = fmaxf(mx, v[jq]);                     \
    mx = fmaxf(mx, __shfl_xor(mx, 16, 64));                                   \
    mx = fmaxf(mx, __shfl_xor(mx, 32, 64));                                   \
    float e[8], sm = 0.f;                                                     \
    _Pragma("unroll")                                                         \
    for (int jq = 0; jq < 8; ++jq) { e[jq] = __expf(v[jq] - mx); sm += e[jq]; } \
    sm += __shfl_xor(sm, 16, 64);                                             \
    sm += __shfl_xor(sm, 32, 64);                                             \
    const float inv = 1.0f / sm;                                              \
    float p[8];                                                               \
    _Pragma("unroll")                                                         \
    for (int jq = 0; jq < 8; ++jq) p[jq] = e[jq] * inv;                       \
    /* out1 via XOR-swizzled LDS transpose ([16][32] f32) -> full-line */     \
    const int r8 = l15 & 7;                                                   \
    *(float4*)&ostW[l15 * 32 + ((quad ^ r8) << 2)] =                          \
        make_float4(p[0], p[1], p[2], p[3]);                                  \
    *(float4*)&ostW[l15 * 32 + (((4 + quad) ^ r8) << 2)] =                    \
        make_float4(p[4], p[5], p[6], p[7]);                                  \
    _Pragma("unroll")                                                         \
    for (int i2 = 0; i2 < 2; ++i2) {                                          \
      const int rr = 8 * i2 + (lane >> 3);                                    \
      const int mm = lane & 7;                                                \
      float4 vv = *(const float4*)&ostW[rr * 32 + ((mm ^ (rr & 7)) << 2)];    \
      *(float4*)(out1 + ((size_t)b * HW + (TBASE) + rr) * SEQQ + mm * 4) = vv;\
    }                                                                         \
  }

// ---------------------------------------------------------------------------
// attn_p1: read-dominated phase (x 134 MB in, out1 16.8 MB out).
// Structure identical to the r4 best kernel minus phase 2.
// ---------------------------------------------------------------------------
extern "C" __global__ __launch_bounds__(256, 2) void attn_p1(
    const float* __restrict__ x,        // [32][4096][256]
    const uint8_t* __restrict__ ws,
    float* __restrict__ out1)           // word_attn [32][4096][32] (fp32 P)
{
  const uint32_t* maskbits_ws = (const uint32_t*)ws;
  const uint16_t* hiT_ws = (const uint16_t*)(ws + 128);
  const uint16_t* loT_ws = hiT_ws + (size_t)BSZ * CTXT_SZ;

  __shared__ __align__(16) uint16_t hiT[CTXT_SZ];      // 16512 B
  __shared__ __align__(16) uint16_t loT[CTXT_SZ];      // 16512 B
  __shared__ __align__(16) float    oStgF[4 * 512];    // 8192 B (2KB/wave)
  __shared__ uint32_t maskW[32];                       // ~41.3 KB total

  const int tid = threadIdx.x;
  const int b   = blockIdx.y;
  const int n0  = blockIdx.x * RPB;

  const int w    = tid >> 6;
  const int lane = tid & 63;
  const int l15  = lane & 15;
  const int quad = lane >> 4;
  const int nwave = n0 + w * 32;
  float* ostW = &oStgF[w * 512];

  const uint4* sHi = (const uint4*)(hiT_ws + (size_t)b * CTXT_SZ);
  const uint4* sLo = (const uint4*)(loT_ws + (size_t)b * CTXT_SZ);

  // ---- issue staging loads (regs) ----
  uint4 hS[4], lS[4];
  #pragma unroll
  for (int k = 0; k < 4; ++k) {
    hS[k] = sHi[tid + k * 256];
    lS[k] = sLo[tid + k * 256];
  }

  // ---- issue ALL tile-0 x loads (16 dwordx4 in flight) ----
  const float* xrow0 = x + ((size_t)b * HW + nwave + l15) * CC + quad * 8;
  float4 xa0[8], xb0[8];
  #pragma unroll
  for (int k0 = 0; k0 < 8; ++k0) {
    xa0[k0] = *(const float4*)(xrow0 + k0 * 32);
    xb0[k0] = *(const float4*)(xrow0 + k0 * 32 + 4);
  }
  asm volatile("" ::: "memory");   // pin: loads above may not sink below

  // ---- LDS writes + barrier ----
  {
    uint4* dHi = (uint4*)hiT;
    uint4* dLo = (uint4*)loT;
    #pragma unroll
    for (int k = 0; k < 4; ++k) {
      dHi[tid + k * 256] = hS[k];
      dLo[tid + k * 256] = lS[k];
    }
    if (tid < 8) { dHi[1024 + tid] = sHi[1024 + tid]; dLo[1024 + tid] = sLo[1024 + tid]; }
    if (tid < 32) maskW[tid] = maskbits_ws[tid];
  }
  __syncthreads();

  // ---- issue ALL tile-1 x loads; latency hides under tile-0 compute ----
  const float* xrow1 = xrow0 + 16 * CC;
  float4 xa1[8], xb1[8];
  #pragma unroll
  for (int k0 = 0; k0 < 8; ++k0) {
    xa1[k0] = *(const float4*)(xrow1 + k0 * 32);
    xb1[k0] = *(const float4*)(xrow1 + k0 * 32 + 4);
  }
  asm volatile("" ::: "memory");

  const int sbase = (l15 >> 2) * SGRP + (l15 & 3) * 16 + (quad >> 1) * 64 + (quad & 1) * 8;

  COMPUTE_TILE_P1(xa0, xb0, nwave);
  COMPUTE_TILE_P1(xa1, xb1, nwave + 16);
}

// ---------------------------------------------------------------------------
// attn_p2: write-dominated phase (out1 ~17 MB + ctx in, out0 134 MB out).
// Reads fp32 P, converts with the SAME f2bf -> pa bits identical to r4's ->
// out0 bit-identical. Lane (l15,quad) loads its own 8 P floats coalesced;
// no pL, no shuffle. Epilogue = r4's full-line LDS transpose.
// ---------------------------------------------------------------------------
extern "C" __global__ __launch_bounds__(256, 4) void attn_p2(
    const float* __restrict__ out1,     // [32][4096][32] fp32 P (input here)
    const uint8_t* __restrict__ ws,
    float* __restrict__ out0)           // weighted_context [32][4096][256]
{
  const uint16_t* hiT_ws = (const uint16_t*)(ws + 128);

  __shared__ __align__(16) uint16_t hiT[CTXT_SZ];      // 16512 B
  __shared__ __align__(16) float    oStgF[4 * 1024];   // 16384 B -> ~33 KB

  const int tid = threadIdx.x;
  const int b   = blockIdx.y;
  const int n0  = blockIdx.x * RPB;

  const int w    = tid >> 6;
  const int lane = tid & 63;
  const int l15  = lane & 15;
  const int quad = lane >> 4;
  const int nwave = n0 + w * 32;
  float* ostW = &oStgF[w * 1024];

  // ---- issue P loads for both tiles (4 dwordx4, in flight across barrier) --
  const float* prow0 = out1 + ((size_t)b * HW + nwave + l15) * SEQQ + quad * 8;
  const float* prow1 = prow0 + 16 * SEQQ;
  float4 q00 = *(const float4*)(prow0);
  float4 q01 = *(const float4*)(prow0 + 4);
  float4 q10 = *(const float4*)(prow1);
  float4 q11 = *(const float4*)(prow1 + 4);
  asm volatile("" ::: "memory");

  // ---- stage ctx hi into LDS ----
  {
    const uint4* sHi = (const uint4*)(hiT_ws + (size_t)b * CTXT_SZ);
    uint4* dHi = (uint4*)hiT;
    #pragma unroll
    for (int k = 0; k < 4; ++k) dHi[tid + k * 256] = sHi[tid + k * 256];
    if (tid < 8) dHi[1024 + tid] = sHi[1024 + tid];
  }
  __syncthreads();

  const int cbase = quad * 2 * SGRP + l15;

  #pragma unroll
  for (int t2 = 0; t2 < 2; ++t2) {
    const float4 qa = t2 ? q10 : q00;
    const float4 qb = t2 ? q11 : q01;
    const int tbase = nwave + t2 * 16;
    union { uint32_t u[4]; short8 s; } pau;
    pau.u[0] = (uint32_t)f2bf(qa.x) | ((uint32_t)f2bf(qa.y) << 16);
    pau.u[1] = (uint32_t)f2bf(qa.z) | ((uint32_t)f2bf(qa.w) << 16);
    pau.u[2] = (uint32_t)f2bf(qb.x) | ((uint32_t)f2bf(qb.y) << 16);
    pau.u[3] = (uint32_t)f2bf(qb.z) | ((uint32_t)f2bf(qb.w) << 16);
    short8 pa = pau.s;

    #pragma unroll
    for (int cg = 0; cg < 4; ++cg) {
      #pragma unroll
      for (int j2 = 0; j2 < 4; ++j2) {
        const int ct = cg * 4 + j2;
        short8 bfr;
        #pragma unroll
        for (int jj = 0; jj < 8; ++jj)
          bfr[jj] = (short)hiT[cbase + (jj >> 2) * SGRP + ct * 64 + (jj & 3) * 16];
        float4v z = {0.f, 0.f, 0.f, 0.f};
        float4v dd = __builtin_amdgcn_mfma_f32_16x16x32_bf16(bfr, pa, z, 0, 0, 0);
        const int ss = j2 * 4 + quad;
        *(float4v*)&ostW[l15 * 64 + ((ss ^ l15) << 2)] = dd;
      }
      #pragma unroll
      for (int i2 = 0; i2 < 4; ++i2) {
        const int rr = 4 * i2 + (lane >> 4);
        const int mm = lane & 15;
        float4 vv = *(const float4*)&ostW[rr * 64 + ((mm ^ rr) << 2)];
        *(float4*)(out0 + ((size_t)b * HW + tbase + rr) * CC + cg * 64 + mm * 4) = vv;
      }
    }
  }
}

// ---------------------------------------------------------------------------
extern "C" void kernel_launch(void* const* d_in, const int* in_sizes, int n_in,
                              void* d_out, int out_size, void* d_ws, size_t ws_size,
                              hipStream_t stream) {
  const float* x      = (const float*)d_in[0];
  // d_in[1] = sentence (unused by reference call())
  const float* ctx_in = (const float*)d_in[2];
  const void*  mask   = d_in[3];
  const float* Wp     = (const float*)d_in[4];

  float* out0 = (float*)d_out;                       // [32][4096][256]
  float* out1 = out0 + (size_t)BSZ * HW * CC;        // [32][4096][32]

  uint8_t*  ws          = (uint8_t*)d_ws;
  uint32_t* maskbits_ws = (uint32_t*)ws;                         // 128 B
  uint16_t* hiT_ws      = (uint16_t*)(ws + 128);                 // 528384 B
  uint16_t* loT_ws      = hiT_ws + (size_t)BSZ * CTXT_SZ;        // 528384 B

  prep_kernel<<<257, 256, 0, stream>>>(ctx_in, Wp, mask, maskbits_ws,
                                       hiT_ws, loT_ws);
  attn_p1<<<dim3(HW / RPB, BSZ), 256, 0, stream>>>(x, ws, out1);
  attn_p2<<<dim3(HW / RPB, BSZ), 256, 0, stream>>>(out1, ws, out0);
}

// Round 10
// 281.660 us; speedup vs baseline: 1.0074x; 1.0074x over previous
//
#include <hip/hip_runtime.h>
#include <stdint.h>

typedef __attribute__((ext_vector_type(8))) short short8;
typedef __attribute__((ext_vector_type(4))) float float4v;

#define HW   4096
#define CC   256
#define SEQQ 32
#define BSZ  32
#define RPB  128   // rows per block (4 waves x 32 rows) -- best-known config

// Tiled ctx layout (per batch): [s>>2][c>>4][s&3][c&15] shorts.
// s-group = 16 c-tiles x 64 = 1024 shorts, padded to 1032 (bank de-phase).
#define SGRP     1032
#define CTXT_SZ  (8 * SGRP)          // 8256 shorts per batch
#define PSTR_P   40                  // pL row stride (shorts)

static __device__ __forceinline__ uint16_t f2bf(float f) {
  union { float f; uint32_t u; } v; v.f = f;
  uint32_t r = v.u + 0x7FFFu + ((v.u >> 16) & 1u);
  return (uint16_t)(r >> 16);
}
static __device__ __forceinline__ float bf2f(uint16_t h) {
  union { uint32_t u; float f; } v; v.u = ((uint32_t)h) << 16;
  return v.f;
}

// ---------------------------------------------------------------------------
// Prep: ctx = context @ W (fp32 accum), split to bf16 hi/lo in TILED layout,
// plus mask -> 32-word bitmask (with storage-format autodetection).
// ---------------------------------------------------------------------------
extern "C" __global__ __launch_bounds__(256) void prep_kernel(
    const float* __restrict__ ctx_in,   // [32][32][256]
    const float* __restrict__ Wp,       // [256][256]
    const void*  __restrict__ mask,     // [32][32] unknown storage
    uint32_t* __restrict__ maskbits_ws, // [32] bitmask words
    uint16_t* __restrict__ hiT_ws,      // [32][8256] tiled bf16 hi
    uint16_t* __restrict__ loT_ws)      // [32][8256] tiled bf16 lo
{
  const int t = threadIdx.x;
  if (blockIdx.x == 256) {
    __shared__ int byteFlag;
    if (t == 0) byteFlag = 0;
    __syncthreads();
    const uint8_t* mb = (const uint8_t*)mask;
    int nz = 0;
    for (int i = t; i < 1024; i += 256)
      if ((i & 3) == 1 && mb[i] != 0) nz = 1;
    if (nz) atomicOr(&byteFlag, 1);
    __syncthreads();
    const bool byteMode = (byteFlag != 0);
    const uint32_t* mw32 = (const uint32_t*)mask;
    if (t < 32) {
      uint32_t bits = 0;
      for (int s = 0; s < 32; ++s) {
        bool m = byteMode ? (mb[t * 32 + s] != 0) : (mw32[t * 32 + s] != 0);
        if (m) bits |= (1u << s);
      }
      maskbits_ws[t] = bits;
    }
    return;
  }

  const int r0 = blockIdx.x * 4;
  __shared__ float crow[4][CC];
  for (int i = t; i < 1024; i += 256)
    crow[i >> 8][i & 255] = ctx_in[(size_t)r0 * CC + i];
  __syncthreads();

  const int j  = t >> 6;
  const int c4 = (t & 63) << 2;
  float4v acc = {0.f, 0.f, 0.f, 0.f};
  #pragma unroll 8
  for (int d = 0; d < CC; ++d) {
    float s = crow[j][d];
    const float4 wv = *(const float4*)&Wp[(size_t)d * CC + c4];
    acc[0] += s * wv.x; acc[1] += s * wv.y;
    acc[2] += s * wv.z; acc[3] += s * wv.w;
  }

  const int row = r0 + j, bb = row >> 5, ss = row & 31;
  const size_t base = (size_t)bb * CTXT_SZ + (ss >> 2) * SGRP + (ss & 3) * 16;
  #pragma unroll
  for (int q = 0; q < 4; ++q) {
    const int c = c4 + q;
    const float v = acc[q];
    const uint16_t h  = f2bf(v);
    const uint16_t lo = f2bf(v - bf2f(h));
    const size_t idx = base + (c >> 4) * 64 + (c & 15);
    hiT_ws[idx] = h;
    loT_ws[idx] = lo;
  }
}

// One 16-row tile. Phase1: split-bf16 MFMA (swapped operands), lane-owns-row
// softmax. out1 and out0 go through per-wave XOR-swizzled LDS transposes so
// every global store instruction covers only FULL 128B lines (the r4 win).
#define COMPUTE_TILE(XA, XB, TBASE)                                           \
  {                                                                           \
    float4v acc0 = {0.f, 0.f, 0.f, 0.f};                                      \
    float4v acc1 = {0.f, 0.f, 0.f, 0.f};                                      \
    _Pragma("unroll")                                                         \
    for (int k0 = 0; k0 < 8; ++k0) {                                          \
      float xv[8] = {XA[k0].x, XA[k0].y, XA[k0].z, XA[k0].w,                  \
                     XB[k0].x, XB[k0].y, XB[k0].z, XB[k0].w};                 \
      short8 ah, al;                                                          \
      _Pragma("unroll")                                                       \
      for (int jj = 0; jj < 8; ++jj) {                                        \
        uint32_t u = __float_as_uint(xv[jj]);                                 \
        ah[jj] = (short)(u >> 16);                                            \
        float rr_ = xv[jj] - __uint_as_float(u & 0xFFFF0000u);                \
        al[jj] = (short)(__float_as_uint(rr_) >> 16);                         \
      }                                                                       \
      const int ka = sbase + k0 * 128;                                        \
      short8 bh0 = *(const short8*)&hiT[ka];                                  \
      short8 bl0 = *(const short8*)&loT[ka];                                  \
      short8 bh1 = *(const short8*)&hiT[ka + 4 * SGRP];                       \
      short8 bl1 = *(const short8*)&loT[ka + 4 * SGRP];                       \
      acc0 = __builtin_amdgcn_mfma_f32_16x16x32_bf16(bh0, ah, acc0, 0, 0, 0); \
      acc0 = __builtin_amdgcn_mfma_f32_16x16x32_bf16(bl0, ah, acc0, 0, 0, 0); \
      acc0 = __builtin_amdgcn_mfma_f32_16x16x32_bf16(bh0, al, acc0, 0, 0, 0); \
      acc1 = __builtin_amdgcn_mfma_f32_16x16x32_bf16(bh1, ah, acc1, 0, 0, 0); \
      acc1 = __builtin_amdgcn_mfma_f32_16x16x32_bf16(bl1, ah, acc1, 0, 0, 0); \
      acc1 = __builtin_amdgcn_mfma_f32_16x16x32_bf16(bh1, al, acc1, 0, 0, 0); \
    }                                                                         \
    const int n = (TBASE) + l15;                                              \
    const uint32_t mwd = maskW[n & 31];                                       \
    float v[8];                                                               \
    _Pragma("unroll")                                                         \
    for (int r = 0; r < 4; ++r) {                                             \
      v[r]     = (mwd & (1u << (quad * 4 + r)))      ? -1e30f : acc0[r];      \
      v[4 + r] = (mwd & (1u << (16 + quad * 4 + r))) ? -1e30f : acc1[r];      \
    }                                                                         \
    float mx = v[0];                                                          \
    _Pragma("unroll")                                                         \
    for (int jq = 1; jq < 8; ++jq) mx = fmaxf(mx, v[jq]);                     \
    mx = fmaxf(mx, __shfl_xor(mx, 16, 64));                                   \
    mx = fmaxf(mx, __shfl_xor(mx, 32, 64));                                   \
    float e[8], sm = 0.f;                                                     \
    _Pragma("unroll")                                                         \
    for (int jq = 0; jq < 8; ++jq) { e[jq] = __expf(v[jq] - mx); sm += e[jq]; } \
    sm += __shfl_xor(sm, 16, 64);                                             \
    sm += __shfl_xor(sm, 32, 64);                                             \
    const float inv = 1.0f / sm;                                              \
    float p[8];                                                               \
    _Pragma("unroll")                                                         \
    for (int jq = 0; jq < 8; ++jq) p[jq] = e[jq] * inv;                       \
    /* out1 via XOR-swizzled LDS transpose ([16][32] f32, 8 slots/row) */     \
    const int r8 = l15 & 7;                                                   \
    *(float4*)&ostW[l15 * 32 + ((quad ^ r8) << 2)] =                          \
        make_float4(p[0], p[1], p[2], p[3]);                                  \
    *(float4*)&ostW[l15 * 32 + (((4 + quad) ^ r8) << 2)] =                    \
        make_float4(p[4], p[5], p[6], p[7]);                                  \
    uint32_t w0 = (uint32_t)f2bf(p[0]) | ((uint32_t)f2bf(p[1]) << 16);        \
    uint32_t w1 = (uint32_t)f2bf(p[2]) | ((uint32_t)f2bf(p[3]) << 16);        \
    uint32_t w2 = (uint32_t)f2bf(p[4]) | ((uint32_t)f2bf(p[5]) << 16);        \
    uint32_t w3 = (uint32_t)f2bf(p[6]) | ((uint32_t)f2bf(p[7]) << 16);        \
    uint16_t* prow = &pL[(w * 16 + l15) * PSTR_P];                            \
    *(uint2*)(prow + quad * 4)      = make_uint2(w0, w1);                     \
    *(uint2*)(prow + 16 + quad * 4) = make_uint2(w2, w3);                     \
    _Pragma("unroll")                                                         \
    for (int i2 = 0; i2 < 2; ++i2) {                                          \
      const int rr = 8 * i2 + (lane >> 3);                                    \
      const int mm = lane & 7;                                                \
      float4 vv = *(const float4*)&ostW[rr * 32 + ((mm ^ (rr & 7)) << 2)];    \
      *(float4*)(out1 + ((size_t)b * HW + (TBASE) + rr) * SEQQ + mm * 4) = vv;\
    }                                                                         \
    /* phase 2: per 64-ch group, MFMA -> LDS transpose -> full-line stores */ \
    short8 pa = *(const short8*)&pL[(w * 16 + l15) * PSTR_P + quad * 8];      \
    _Pragma("unroll")                                                         \
    for (int cg = 0; cg < 4; ++cg) {                                          \
      _Pragma("unroll")                                                       \
      for (int j2 = 0; j2 < 4; ++j2) {                                        \
        const int ct = cg * 4 + j2;                                           \
        short8 bfr;                                                           \
        _Pragma("unroll")                                                     \
        for (int jj = 0; jj < 8; ++jj)                                        \
          bfr[jj] = (short)hiT[cbase + (jj >> 2) * SGRP + ct * 64 + (jj & 3) * 16]; \
        float4v z = {0.f, 0.f, 0.f, 0.f};                                     \
        float4v dd = __builtin_amdgcn_mfma_f32_16x16x32_bf16(bfr, pa, z, 0, 0, 0); \
        const int ss = j2 * 4 + quad;                                         \
        *(float4v*)&ostW[l15 * 64 + ((ss ^ l15) << 2)] = dd;                  \
      }                                                                       \
      _Pragma("unroll")                                                       \
      for (int i2 = 0; i2 < 4; ++i2) {                                        \
        const int rr = 4 * i2 + (lane >> 4);                                  \
        const int mm = lane & 15;                                             \
        float4 vv = *(const float4*)&ostW[rr * 64 + ((mm ^ rr) << 2)];        \
        *(float4*)(out0 + ((size_t)b * HW + (TBASE) + rr) * CC + cg * 64 + mm * 4) = vv; \
      }                                                                       \
    }                                                                         \
  }

// ---------------------------------------------------------------------------
// Main fused kernel -- the session's best-known configuration (r4):
// 1024 blocks, 2 blocks/CU, 4 waves x 2 tiles, all-loads-in-flight prologue,
// single barrier, full-128B-line store epilogues via LDS transpose.
// ---------------------------------------------------------------------------
extern "C" __global__ __launch_bounds__(256, 2) void attn_main(
    const float* __restrict__ x,        // [32][4096][256]
    const uint8_t* __restrict__ ws,
    float* __restrict__ out0,           // weighted_context [32][4096][256]
    float* __restrict__ out1)           // word_attn        [32][4096][32]
{
  const uint32_t* maskbits_ws = (const uint32_t*)ws;
  const uint16_t* hiT_ws = (const uint16_t*)(ws + 128);
  const uint16_t* loT_ws = hiT_ws + (size_t)BSZ * CTXT_SZ;

  __shared__ __align__(16) uint16_t hiT[CTXT_SZ];      // 16512 B
  __shared__ __align__(16) uint16_t loT[CTXT_SZ];      // 16512 B
  __shared__ __align__(16) uint16_t pL[64 * PSTR_P];   // 5120 B
  __shared__ __align__(16) float    oStgF[4 * 1024];   // 16384 B (4KB/wave)
  __shared__ uint32_t maskW[32];

  const int tid = threadIdx.x;
  const int b   = blockIdx.y;
  const int n0  = blockIdx.x * RPB;

  const int w    = tid >> 6;
  const int lane = tid & 63;
  const int l15  = lane & 15;
  const int quad = lane >> 4;
  const int nwave = n0 + w * 32;
  float* ostW = &oStgF[w * 1024];

  const uint4* sHi = (const uint4*)(hiT_ws + (size_t)b * CTXT_SZ);
  const uint4* sLo = (const uint4*)(loT_ws + (size_t)b * CTXT_SZ);

  // ---- issue staging loads (regs) ----
  uint4 hS[4], lS[4];
  #pragma unroll
  for (int k = 0; k < 4; ++k) {
    hS[k] = sHi[tid + k * 256];
    lS[k] = sLo[tid + k * 256];
  }

  // ---- issue ALL tile-0 x loads (16 dwordx4 in flight) ----
  const float* xrow0 = x + ((size_t)b * HW + nwave + l15) * CC + quad * 8;
  float4 xa0[8], xb0[8];
  #pragma unroll
  for (int k0 = 0; k0 < 8; ++k0) {
    xa0[k0] = *(const float4*)(xrow0 + k0 * 32);
    xb0[k0] = *(const float4*)(xrow0 + k0 * 32 + 4);
  }
  asm volatile("" ::: "memory");   // pin: loads above may not sink below

  // ---- LDS writes + barrier ----
  {
    uint4* dHi = (uint4*)hiT;
    uint4* dLo = (uint4*)loT;
    #pragma unroll
    for (int k = 0; k < 4; ++k) {
      dHi[tid + k * 256] = hS[k];
      dLo[tid + k * 256] = lS[k];
    }
    if (tid < 8) { dHi[1024 + tid] = sHi[1024 + tid]; dLo[1024 + tid] = sLo[1024 + tid]; }
    if (tid < 32) maskW[tid] = maskbits_ws[tid];
  }
  __syncthreads();

  // ---- issue ALL tile-1 x loads; latency hides under tile-0 compute ----
  const float* xrow1 = xrow0 + 16 * CC;
  float4 xa1[8], xb1[8];
  #pragma unroll
  for (int k0 = 0; k0 < 8; ++k0) {
    xa1[k0] = *(const float4*)(xrow1 + k0 * 32);
    xb1[k0] = *(const float4*)(xrow1 + k0 * 32 + 4);
  }
  asm volatile("" ::: "memory");   // pin: tile-1 loads issue before t0 compute

  const int sbase = (l15 >> 2) * SGRP + (l15 & 3) * 16 + (quad >> 1) * 64 + (quad & 1) * 8;
  const int cbase = quad * 2 * SGRP + l15;

  COMPUTE_TILE(xa0, xb0, nwave);
  COMPUTE_TILE(xa1, xb1, nwave + 16);
}

// ---------------------------------------------------------------------------
extern "C" void kernel_launch(void* const* d_in, const int* in_sizes, int n_in,
                              void* d_out, int out_size, void* d_ws, size_t ws_size,
                              hipStream_t stream) {
  const float* x      = (const float*)d_in[0];
  // d_in[1] = sentence (unused by reference call())
  const float* ctx_in = (const float*)d_in[2];
  const void*  mask   = d_in[3];
  const float* Wp     = (const float*)d_in[4];

  float* out0 = (float*)d_out;                       // [32][4096][256]
  float* out1 = out0 + (size_t)BSZ * HW * CC;        // [32][4096][32]

  uint8_t*  ws          = (uint8_t*)d_ws;
  uint32_t* maskbits_ws = (uint32_t*)ws;                         // 128 B
  uint16_t* hiT_ws      = (uint16_t*)(ws + 128);                 // 528384 B
  uint16_t* loT_ws      = hiT_ws + (size_t)BSZ * CTXT_SZ;        // 528384 B

  prep_kernel<<<257, 256, 0, stream>>>(ctx_in, Wp, mask, maskbits_ws,
                                       hiT_ws, loT_ws);
  attn_main<<<dim3(HW / RPB, BSZ), 256, 0, stream>>>(x, ws, out0, out1);
}